// Round 8
// baseline (1203.694 us; speedup 1.0000x reference)
//
#include <hip/hip_runtime.h>
#include <stdint.h>

// MMoE: M=8192 tokens, D=1024, F=4096, E=8 experts, T=4 tasks.
// out[tok] = sum_e gate[tok,e] * (relu(x@w1[e]+b1[e]) @ w2[e] + b2[e]); gate=0 row if b_seq==0.
// R8 = R6 (serial dispatches, MC=1024 L3-resident phases, compaction, bf16 partials)
//      + C^T epilogue: MFMA operands swapped -> per-lane 4 consecutive N-cols ->
//        packed v_cvt_pk_bf16_f32 + dwordx2 stores (4x fewer store instructions).
//      R7's concurrent gemm1+gemm2 fusion REVERTED (merged working set 290MB > L3 -> thrash).

#define MTOK 8192
#define DMODEL 1024
#define DFF 4096
#define NEXP 8

typedef __attribute__((ext_vector_type(8))) short bf16x8;
typedef __attribute__((ext_vector_type(4))) float f32x4;
typedef __attribute__((ext_vector_type(4))) unsigned short u16x4;

typedef const __attribute__((address_space(1))) void* gas_ptr;
typedef __attribute__((address_space(3))) void* las_ptr;

__device__ __forceinline__ ushort f32_bf16(float f) {
  uint32_t u = __builtin_bit_cast(uint32_t, f);
  return (ushort)((u + 0x7FFFu + ((u >> 16) & 1u)) >> 16);
}

__device__ __forceinline__ float bf16_f32(ushort u) {
  return __builtin_bit_cast(float, (uint32_t)u << 16);
}

__device__ __forceinline__ uint32_t pk_bf16(float lo, float hi) {
  uint32_t d;
  asm("v_cvt_pk_bf16_f32 %0, %1, %2" : "=v"(d) : "v"(lo), "v"(hi));
  return d;
}

__device__ __forceinline__ void gload_lds16(const void* g, void* s) {
  __builtin_amdgcn_global_load_lds((gas_ptr)g, (las_ptr)s, 16, 0, 0);
}

__device__ __forceinline__ unsigned ldsOff(const void* p) {
  return (unsigned)(unsigned long long)(__attribute__((address_space(3))) const char*)p;
}

// ---------------- gates: one wave per token ----------------
__global__ __launch_bounds__(256) void gates_kernel(
    const float* __restrict__ x, const int* __restrict__ b_seq,
    const float* __restrict__ w_gates, float* __restrict__ g) {
  int wave = threadIdx.x >> 6;
  int lane = threadIdx.x & 63;
  int tok = blockIdx.x * 4 + wave;
  if (tok >= MTOK) return;
  int t = b_seq[tok];
  if (t == 0) {
    if (lane < 8) g[tok * 8 + lane] = 0.f;
    return;
  }
  const float* wg = w_gates + (size_t)(t - 1) * DMODEL * NEXP;
  const float* xr = x + (size_t)tok * DMODEL;
  float acc[8] = {0.f, 0.f, 0.f, 0.f, 0.f, 0.f, 0.f, 0.f};
  for (int d = lane; d < DMODEL; d += 64) {
    float xv = xr[d];
    const float* w = wg + (size_t)d * NEXP;
#pragma unroll
    for (int e = 0; e < 8; ++e) acc[e] = fmaf(xv, w[e], acc[e]);
  }
#pragma unroll
  for (int off = 32; off; off >>= 1) {
#pragma unroll
    for (int e = 0; e < 8; ++e) acc[e] += __shfl_xor(acc[e], off, 64);
  }
  if (lane == 0) {
    float m = acc[0];
#pragma unroll
    for (int e = 1; e < 8; ++e) m = fmaxf(m, acc[e]);
    float p[8]; float s = 0.f;
#pragma unroll
    for (int e = 0; e < 8; ++e) { p[e] = expf(acc[e] - m); s += p[e]; }
    float inv = 1.f / s;
#pragma unroll
    for (int e = 0; e < 8; ++e) g[tok * 8 + e] = p[e] * inv;
  }
}

// ---------------- compaction scan: deterministic, 1 block ----------------
__global__ __launch_bounds__(1024) void scan_kernel(
    const int* __restrict__ b_seq, const float* __restrict__ g,
    int* __restrict__ orig, float* __restrict__ g_c, int* __restrict__ cnt2) {
  __shared__ int s[1024];
  int t = threadIdx.x;
  int f[8]; int loc = 0;
  int base_tok = t * 8;
#pragma unroll
  for (int j = 0; j < 8; ++j) { f[j] = b_seq[base_tok + j] > 0; loc += f[j]; }
  s[t] = loc;
  __syncthreads();
  for (int off = 1; off < 1024; off <<= 1) {
    int v = (t >= off) ? s[t - off] : 0;
    __syncthreads();
    s[t] += v;
    __syncthreads();
  }
  int pos = s[t] - loc;
#pragma unroll
  for (int j = 0; j < 8; ++j) {
    if (f[j]) {
      orig[pos] = base_tok + j;
#pragma unroll
      for (int e = 0; e < 8; ++e) g_c[pos * 8 + e] = g[(base_tok + j) * 8 + e];
      pos++;
    }
  }
  if (t == 1023) {
    int count = s[1023];
    cnt2[0] = count;
    cnt2[1] = (count + 255) & ~255;
  }
}

// ---------------- cast x f32 -> bf16 (fallback path only) ----------------
__global__ __launch_bounds__(256) void cast_x_kernel(
    const float* __restrict__ x, ushort* __restrict__ xb, int n4) {
  int idx = blockIdx.x * blockDim.x + threadIdx.x;
  int stride = gridDim.x * blockDim.x;
  for (; idx < n4; idx += stride) {
    float4 v = ((const float4*)x)[idx];
    ushort4 o;
    o.x = f32_bf16(v.x); o.y = f32_bf16(v.y); o.z = f32_bf16(v.z); o.w = f32_bf16(v.w);
    ((ushort4*)xb)[idx] = o;
  }
}

// ------- gather + cast: x_c[r] = bf16(x[orig[r]]); zero pad rows (x and gates) -------
__global__ __launch_bounds__(256) void gather_cast_kernel(
    const float* __restrict__ x, const int* __restrict__ orig,
    const int* __restrict__ cnt2, ushort* __restrict__ x_c, float* __restrict__ g_c) {
  int r = blockIdx.x * 8 + (threadIdx.x >> 5);
  int cpad = cnt2[1];
  if (r >= cpad) return;
  int count = cnt2[0];
  int lane32 = threadIdx.x & 31;
  ushort4* dst = (ushort4*)(x_c + (size_t)r * DMODEL);
  if (r < count) {
    const float4* src = (const float4*)(x + (size_t)orig[r] * DMODEL);
    for (int j = lane32; j < 256; j += 32) {
      float4 v = src[j];
      ushort4 o;
      o.x = f32_bf16(v.x); o.y = f32_bf16(v.y); o.z = f32_bf16(v.z); o.w = f32_bf16(v.w);
      dst[j] = o;
    }
  } else {
    ushort4 z = {0, 0, 0, 0};
    for (int j = lane32; j < 256; j += 32) dst[j] = z;
    if (lane32 < 8) g_c[(size_t)r * 8 + lane32] = 0.f;
  }
}

// ---- transpose+cast: src f32 [R][C] -> dst bf16 [C][R] with dst ld + per-expert strides ----
__global__ __launch_bounds__(256) void transpose_cast_kernel(
    const float* __restrict__ src0, ushort* __restrict__ dst0, int R, int C,
    int ld_dst, size_t src_estride, size_t dst_estride) {
  const float* src = src0 + blockIdx.z * src_estride;
  ushort* dst = dst0 + blockIdx.z * dst_estride;
  __shared__ float tile[32][33];
  int tr = blockIdx.y, tc = blockIdx.x;
  int t = threadIdx.x;
  int r = t >> 3, c4 = (t & 7) * 4;
  float4 v = *(const float4*)&src[(size_t)(tr * 32 + r) * C + tc * 32 + c4];
  tile[r][c4 + 0] = v.x; tile[r][c4 + 1] = v.y; tile[r][c4 + 2] = v.z; tile[r][c4 + 3] = v.w;
  __syncthreads();
  ushort4 o;
  o.x = f32_bf16(tile[c4 + 0][r]);
  o.y = f32_bf16(tile[c4 + 1][r]);
  o.z = f32_bf16(tile[c4 + 2][r]);
  o.w = f32_bf16(tile[c4 + 3][r]);
  *(ushort4*)&dst[(size_t)(tc * 32 + r) * ld_dst + tr * 32 + c4] = o;
}

// ---------------- out init: out[n,d] = sum_e g[n,e]*b2[e,d] ----------------
__global__ __launch_bounds__(256) void bias_init_kernel(
    const float* __restrict__ g, const float* __restrict__ b2, float* __restrict__ out) {
  int idx = blockIdx.x * 256 + threadIdx.x;
  int tok = idx >> 10, d = idx & 1023;
  const float* gr = g + (size_t)tok * 8;
  float s = 0.f;
#pragma unroll
  for (int e = 0; e < 8; ++e) s = fmaf(gr[e], b2[(size_t)e * DMODEL + d], s);
  out[idx] = s;
}

// ================= 256x256 8-phase GEMM (BK=64, 8 waves, 128KB LDS dbuf) =================
// MFMA operands SWAPPED (mfma(B,A)) -> C^T fragment: per lane, q = 4 CONSECUTIVE N-cols
// -> packed cvt_pk + dwordx2 epilogue stores.
// EPI=1: H = gate * relu(A@Bt^T + b1)  (bf16, ld 32768)
// EPI=2: partial[z] = A@Bt^T over K-slice (bf16, ld 1024)
#define DS_READ(dst, addr) asm volatile("ds_read_b128 %0, %1" : "=v"(dst) : "v"(addr))

#define MFMA16(mh, BF) do { \
  acc[(mh)*4+0][0] = __builtin_amdgcn_mfma_f32_16x16x32_bf16(BF[0], aF[0], acc[(mh)*4+0][0],0,0,0); \
  acc[(mh)*4+0][1] = __builtin_amdgcn_mfma_f32_16x16x32_bf16(BF[1], aF[0], acc[(mh)*4+0][1],0,0,0); \
  acc[(mh)*4+0][2] = __builtin_amdgcn_mfma_f32_16x16x32_bf16(BF[2], aF[0], acc[(mh)*4+0][2],0,0,0); \
  acc[(mh)*4+0][3] = __builtin_amdgcn_mfma_f32_16x16x32_bf16(BF[3], aF[0], acc[(mh)*4+0][3],0,0,0); \
  acc[(mh)*4+1][0] = __builtin_amdgcn_mfma_f32_16x16x32_bf16(BF[0], aF[1], acc[(mh)*4+1][0],0,0,0); \
  acc[(mh)*4+1][1] = __builtin_amdgcn_mfma_f32_16x16x32_bf16(BF[1], aF[1], acc[(mh)*4+1][1],0,0,0); \
  acc[(mh)*4+1][2] = __builtin_amdgcn_mfma_f32_16x16x32_bf16(BF[2], aF[1], acc[(mh)*4+1][2],0,0,0); \
  acc[(mh)*4+1][3] = __builtin_amdgcn_mfma_f32_16x16x32_bf16(BF[3], aF[1], acc[(mh)*4+1][3],0,0,0); \
  acc[(mh)*4+2][0] = __builtin_amdgcn_mfma_f32_16x16x32_bf16(BF[0], aF[2], acc[(mh)*4+2][0],0,0,0); \
  acc[(mh)*4+2][1] = __builtin_amdgcn_mfma_f32_16x16x32_bf16(BF[1], aF[2], acc[(mh)*4+2][1],0,0,0); \
  acc[(mh)*4+2][2] = __builtin_amdgcn_mfma_f32_16x16x32_bf16(BF[2], aF[2], acc[(mh)*4+2][2],0,0,0); \
  acc[(mh)*4+2][3] = __builtin_amdgcn_mfma_f32_16x16x32_bf16(BF[3], aF[2], acc[(mh)*4+2][3],0,0,0); \
  acc[(mh)*4+3][0] = __builtin_amdgcn_mfma_f32_16x16x32_bf16(BF[0], aF[3], acc[(mh)*4+3][0],0,0,0); \
  acc[(mh)*4+3][1] = __builtin_amdgcn_mfma_f32_16x16x32_bf16(BF[1], aF[3], acc[(mh)*4+3][1],0,0,0); \
  acc[(mh)*4+3][2] = __builtin_amdgcn_mfma_f32_16x16x32_bf16(BF[2], aF[3], acc[(mh)*4+3][2],0,0,0); \
  acc[(mh)*4+3][3] = __builtin_amdgcn_mfma_f32_16x16x32_bf16(BF[3], aF[3], acc[(mh)*4+3][3],0,0,0); \
} while (0)

#define PH_READS_A(mh, kx) do { \
  DS_READ(aF[0], ab + (mh)*8192 +    0 + (kx)); \
  DS_READ(aF[1], ab + (mh)*8192 + 2048 + (kx)); \
  DS_READ(aF[2], ab + (mh)*8192 + 4096 + (kx)); \
  DS_READ(aF[3], ab + (mh)*8192 + 6144 + (kx)); \
} while (0)

#define PH_READS_B(BF, kx) do { \
  DS_READ(BF[0], bb +    0 + (kx)); \
  DS_READ(BF[1], bb + 2048 + (kx)); \
  DS_READ(BF[2], bb + 4096 + (kx)); \
  DS_READ(BF[3], bb + 6144 + (kx)); \
} while (0)

#define PH_TAIL(mh, BF, CLOSE) do { \
  __builtin_amdgcn_s_barrier(); \
  asm volatile("s_waitcnt lgkmcnt(0)" ::: "memory"); \
  __builtin_amdgcn_sched_barrier(0); \
  __builtin_amdgcn_s_setprio(1); \
  MFMA16(mh, BF); \
  __builtin_amdgcn_s_setprio(0); \
  if (CLOSE) __builtin_amdgcn_s_barrier(); \
} while (0)

template <int EPI>
__global__ __launch_bounds__(512, 2) void gemm8p(
    const ushort* __restrict__ A, const ushort* __restrict__ Bt,
    int ldA, int ldB, int K_len,
    const float* __restrict__ Bias, const float* __restrict__ Gates,
    ushort* __restrict__ H, int m_off,
    ushort* __restrict__ PoutBf, size_t PsliceElems,
    const int* __restrict__ cnt2) {
  // compaction guard: skip M-tiles beyond padded count (block-uniform, before any barrier)
  if (m_off + (int)blockIdx.y * 256 >= cnt2[1]) return;

  __shared__ __align__(16) char lds[131072];
  const int tid = threadIdx.x;
  const int lane = tid & 63;
  const int wid = tid >> 6;
  const int wm = wid >> 2;   // 0..1
  const int wn = wid & 3;    // 0..3
  const int tileM = blockIdx.y * 256;
  const int tileN = blockIdx.x * 256;
  const int kbeg = blockIdx.z * K_len;

  const ushort* Arow0 = A + (size_t)tileM * ldA + kbeg;
  const ushort* Brow0 = Bt + (size_t)tileN * ldB + kbeg;
  char* ldsc = (char*)lds;
  const unsigned lds0 = ldsOff(lds);
  const unsigned abase = lds0 + (wm * 128 + (lane & 15)) * 128;
  const unsigned bbase = lds0 + 32768 + (wn * 64 + (lane & 15)) * 128;
  const unsigned kx0 = (unsigned)(((lane >> 4) << 4) ^ ((lane & 7) << 4));
  const unsigned kx1 = kx0 ^ 64u;

  f32x4 acc[8][4];
#pragma unroll
  for (int i = 0; i < 8; ++i)
#pragma unroll
    for (int j = 0; j < 4; ++j) acc[i][j] = (f32x4){0.f, 0.f, 0.f, 0.f};

  const int rr = tid >> 3;
  const int scol = ((tid & 7) << 4) ^ ((rr & 7) << 4);
  auto STAGE = [&](int buf, int isB, int hh, int kt2) {
    const ushort* gsrc = isB ? Brow0 : Arow0;
    const int ld = isB ? ldB : ldA;
    char* region = ldsc + buf * 65536 + isB * 32768 + hh * 16384;
#pragma unroll
    for (int j = 0; j < 2; ++j) {
      int row = j * 64 + rr;
      const char* src = (const char*)(gsrc + (size_t)(hh * 128 + row) * ld + kt2 * 64) + scol;
      gload_lds16(src, region + (j * 512 + tid) * 16);
    }
  };

  bf16x8 aF[4], bF0[4], bF1[4];
  const int NT = K_len >> 6;

  STAGE(0, 1, 0, 0); STAGE(0, 1, 1, 0); STAGE(0, 0, 0, 0); STAGE(0, 0, 1, 0);
  if (NT > 1) STAGE(1, 1, 0, 1);
  asm volatile("s_waitcnt vmcnt(2)" ::: "memory");
  __builtin_amdgcn_s_barrier();

  for (int kt = 0; kt < NT; ++kt) {
    const int cur = kt & 1;
    const int oth = cur ^ 1;
    const unsigned bufoff = (unsigned)cur << 16;
    const unsigned ab = abase + bufoff;
    const unsigned bb = bbase + bufoff;
    const bool s1 = (kt + 1 < NT), s2 = (kt + 2 < NT);
    PH_READS_A(0, kx0); PH_READS_B(bF0, kx0);
    if (s1) STAGE(oth, 1, 1, kt + 1);
    PH_TAIL(0, bF0, true);
    PH_READS_A(1, kx0);
    if (s1) STAGE(oth, 0, 0, kt + 1);
    PH_TAIL(1, bF0, true);
    PH_READS_A(0, kx1); PH_READS_B(bF1, kx1);
    if (s1) STAGE(oth, 0, 1, kt + 1);
    PH_TAIL(0, bF1, true);
    PH_READS_A(1, kx1);
    if (s2) STAGE(cur, 1, 0, kt + 2);
    PH_TAIL(1, bF1, false);
    if (s1) {
      if (s2) asm volatile("s_waitcnt vmcnt(2)" ::: "memory");
      else    asm volatile("s_waitcnt vmcnt(0)" ::: "memory");
      __builtin_amdgcn_s_barrier();
    }
  }

  // ---- C^T-fragment epilogue: per lane, row = lane&15 (M), q = 4 consecutive cols (N) ----
  const int rowB = tileM + wm * 128 + (lane & 15);
  const int colB = tileN + wn * 64 + ((lane >> 4) << 2);
  if constexpr (EPI == 1) {
    const int e = tileN >> 12;  // 256-wide tile never crosses expert boundary
    float4 b4[4];
#pragma unroll
    for (int nf = 0; nf < 4; ++nf) b4[nf] = *(const float4*)&Bias[colB + nf * 16];
#pragma unroll
    for (int mf = 0; mf < 8; ++mf) {
      const int row = rowB + mf * 16;
      const float gv = Gates[(size_t)(m_off + row) * 8 + e];
#pragma unroll
      for (int nf = 0; nf < 4; ++nf) {
        float v0 = fmaxf(acc[mf][nf][0] + b4[nf].x, 0.f) * gv;
        float v1 = fmaxf(acc[mf][nf][1] + b4[nf].y, 0.f) * gv;
        float v2 = fmaxf(acc[mf][nf][2] + b4[nf].z, 0.f) * gv;
        float v3 = fmaxf(acc[mf][nf][3] + b4[nf].w, 0.f) * gv;
        uint2 st = {pk_bf16(v0, v1), pk_bf16(v2, v3)};
        *(uint2*)&H[(size_t)row * 32768 + colB + nf * 16] = st;
      }
    }
  } else {
    ushort* Pb = PoutBf + (size_t)blockIdx.z * PsliceElems;
#pragma unroll
    for (int mf = 0; mf < 8; ++mf) {
      const int row = rowB + mf * 16;
#pragma unroll
      for (int nf = 0; nf < 4; ++nf) {
        uint2 st = {pk_bf16(acc[mf][nf][0], acc[mf][nf][1]),
                    pk_bf16(acc[mf][nf][2], acc[mf][nf][3])};
        *(uint2*)&Pb[(size_t)row * 1024 + colB + nf * 16] = st;
      }
    }
  }
}

// ------- reduce: out[orig[gr]] += sum_s part[s][r]  (bf16 partials, scatter, count guard) -------
__global__ __launch_bounds__(256) void reduce_kernel(
    const ushort* __restrict__ Pb, float* __restrict__ out,
    const int* __restrict__ orig, const int* __restrict__ cnt2,
    int m_off, int S, size_t sstride) {
  int i = blockIdx.x * 256 + threadIdx.x;
  int r = i >> 8;
  int d4 = i & 255;
  int gr = m_off + r;
  if (gr >= cnt2[0]) return;
  float4* orow = (float4*)(out + (size_t)orig[gr] * 1024);
  float4 a = orow[d4];
  for (int s = 0; s < S; ++s) {
    u16x4 v = *((const u16x4*)(Pb + (size_t)s * sstride + (size_t)r * 1024) + d4);
    a.x += bf16_f32(v.x); a.y += bf16_f32(v.y); a.z += bf16_f32(v.z); a.w += bf16_f32(v.w);
  }
  orow[d4] = a;
}

// ================= R1 fallback kernels (128x128, m97-structure) =================
__global__ __launch_bounds__(256) void gemm1_kernel(
    const ushort* __restrict__ A, const ushort* __restrict__ Bt,
    const float* __restrict__ b1e, const float* __restrict__ g,
    ushort* __restrict__ H, int m_off, int e) {
  __shared__ ushort As[128 * 32];
  __shared__ ushort Bs[128 * 32];
  const int tid = threadIdx.x;
  const int lane = tid & 63;
  const int wid = tid >> 6;
  const int wm = wid >> 1, wn = wid & 1;
  const int tileM = blockIdx.y * 128;
  const int tileN = blockIdx.x * 128;
  f32x4 zero = {0.f, 0.f, 0.f, 0.f};
  f32x4 acc[4][4];
#pragma unroll
  for (int i = 0; i < 4; ++i)
#pragma unroll
    for (int j = 0; j < 4; ++j) acc[i][j] = zero;
  const int r0 = tid >> 2;
  const int cb = (tid & 3) << 4;
  const char* gA = (const char*)(A + (size_t)(tileM + r0) * DMODEL) + cb;
  const char* gB = (const char*)(Bt + (size_t)(tileN + r0) * DMODEL) + cb;
  char* lA = (char*)As + r0 * 64 + cb;
  char* lB = (char*)Bs + r0 * 64 + cb;
  const int lrow = lane & 15;
  const int lk = (lane >> 4) << 3;
  for (int k0 = 0; k0 < DMODEL; k0 += 32) {
    const size_t kb = (size_t)k0 * 2;
    gload_lds16(gA + kb, lA);
    gload_lds16(gA + kb + (size_t)64 * DMODEL * 2, lA + 4096);
    gload_lds16(gB + kb, lB);
    gload_lds16(gB + kb + (size_t)64 * DMODEL * 2, lB + 4096);
    __syncthreads();
    bf16x8 af[4], bfv[4];
#pragma unroll
    for (int i = 0; i < 4; ++i) {
      af[i] = *(const bf16x8*)&As[(wm * 64 + i * 16 + lrow) * 32 + lk];
      bfv[i] = *(const bf16x8*)&Bs[(wn * 64 + i * 16 + lrow) * 32 + lk];
    }
#pragma unroll
    for (int i = 0; i < 4; ++i)
#pragma unroll
      for (int j = 0; j < 4; ++j)
        acc[i][j] = __builtin_amdgcn_mfma_f32_16x16x32_bf16(af[i], bfv[j], acc[i][j], 0, 0, 0);
    __syncthreads();
  }
#pragma unroll
  for (int i = 0; i < 4; ++i) {
#pragma unroll
    for (int j = 0; j < 4; ++j) {
      int col = tileN + wn * 64 + j * 16 + (lane & 15);
      float bias = b1e[col];
#pragma unroll
      for (int q = 0; q < 4; ++q) {
        int row = tileM + wm * 64 + i * 16 + ((lane >> 4) << 2) + q;
        float gv = g[(size_t)(m_off + row) * 8 + e];
        float v = fmaxf(acc[i][j][q] + bias, 0.f) * gv;
        H[(size_t)row * DFF + col] = f32_bf16(v);
      }
    }
  }
}

__global__ __launch_bounds__(256) void gemm2_kernel(
    const ushort* __restrict__ A, const ushort* __restrict__ Bt,
    float* __restrict__ out) {
  __shared__ ushort As[128 * 32];
  __shared__ ushort Bs[128 * 32];
  const int tid = threadIdx.x;
  const int lane = tid & 63;
  const int wid = tid >> 6;
  const int wm = wid >> 1, wn = wid & 1;
  const int tileM = blockIdx.y * 128;
  const int tileN = blockIdx.x * 128;
  f32x4 zero = {0.f, 0.f, 0.f, 0.f};
  f32x4 acc[4][4];
#pragma unroll
  for (int i = 0; i < 4; ++i)
#pragma unroll
    for (int j = 0; j < 4; ++j) acc[i][j] = zero;
  const int r0 = tid >> 2;
  const int cb = (tid & 3) << 4;
  const char* gA = (const char*)(A + (size_t)(tileM + r0) * DFF) + cb;
  const char* gB = (const char*)(Bt + (size_t)(tileN + r0) * DFF) + cb;
  char* lA = (char*)As + r0 * 64 + cb;
  char* lB = (char*)Bs + r0 * 64 + cb;
  const int lrow = lane & 15;
  const int lk = (lane >> 4) << 3;
  for (int k0 = 0; k0 < DFF; k0 += 32) {
    const size_t kb = (size_t)k0 * 2;
    gload_lds16(gA + kb, lA);
    gload_lds16(gA + kb + (size_t)64 * DFF * 2, lA + 4096);
    gload_lds16(gB + kb, lB);
    gload_lds16(gB + kb + (size_t)64 * DFF * 2, lB + 4096);
    __syncthreads();
    bf16x8 af[4], bfv[4];
#pragma unroll
    for (int i = 0; i < 4; ++i) {
      af[i] = *(const bf16x8*)&As[(wm * 64 + i * 16 + lrow) * 32 + lk];
      bfv[i] = *(const bf16x8*)&Bs[(wn * 64 + i * 16 + lrow) * 32 + lk];
    }
#pragma unroll
    for (int i = 0; i < 4; ++i)
#pragma unroll
      for (int j = 0; j < 4; ++j)
        acc[i][j] = __builtin_amdgcn_mfma_f32_16x16x32_bf16(af[i], bfv[j], acc[i][j], 0, 0, 0);
    __syncthreads();
  }
#pragma unroll
  for (int i = 0; i < 4; ++i) {
#pragma unroll
    for (int j = 0; j < 4; ++j) {
      int col = tileN + wn * 64 + j * 16 + (lane & 15);
#pragma unroll
      for (int q = 0; q < 4; ++q) {
        int row = tileM + wm * 64 + i * 16 + ((lane >> 4) << 2) + q;
        size_t o = (size_t)row * DMODEL + col;
        out[o] += acc[i][j][q];
      }
    }
  }
}

extern "C" void kernel_launch(void* const* d_in, const int* in_sizes, int n_in,
                              void* d_out, int out_size, void* d_ws, size_t ws_size,
                              hipStream_t stream) {
  const float* x = (const float*)d_in[0];
  const int* b_seq = (const int*)d_in[1];
  const float* w1 = (const float*)d_in[2];
  const float* b1 = (const float*)d_in[3];
  const float* w2 = (const float*)d_in[4];
  const float* b2 = (const float*)d_in[5];
  const float* w_gates = (const float*)d_in[6];
  float* out = (float*)d_out;

  char* ws = (char*)d_ws;
  size_t off = 0;
  auto alloc = [&](size_t bytes) {
    char* p = ws + off;
    off += (bytes + 255) & ~(size_t)255;
    return p;
  };

  const int MC = 1024, S = 16, KS = 2048;
  const size_t need_fused =
      (size_t)MTOK * 8 * 4 + 512 +            // g
      (size_t)MTOK * 4 + 512 +                // orig
      1024 +                                  // cnt2
      (size_t)MTOK * 8 * 4 + 512 +            // g_c
      (size_t)MTOK * DMODEL * 2 + 512 +       // x_c
      (size_t)NEXP * DFF * DMODEL * 2 + 512 + // w1t_all
      (size_t)NEXP * DFF * DMODEL * 2 + 512 + // w2t_all
      (size_t)MC * NEXP * DFF * 2 + 512 +     // h chunk (64 MB)
      (size_t)S * MC * DMODEL * 2 + 512;      // bf16 partials (32 MB)

  if (ws_size >= need_fused) {
    float* g = (float*)alloc((size_t)MTOK * 8 * 4);
    int* orig = (int*)alloc((size_t)MTOK * 4);
    int* cnt2 = (int*)alloc(64);
    float* g_c = (float*)alloc((size_t)MTOK * 8 * 4);
    ushort* x_c = (ushort*)alloc((size_t)MTOK * DMODEL * 2);
    ushort* w1t_all = (ushort*)alloc((size_t)NEXP * DFF * DMODEL * 2);  // [E*F][D]
    ushort* w2t_all = (ushort*)alloc((size_t)DMODEL * NEXP * DFF * 2);  // [D][E*F]
    ushort* h_all = (ushort*)alloc((size_t)MC * NEXP * DFF * 2);        // [MC][E*F]
    ushort* part = (ushort*)alloc((size_t)S * MC * DMODEL * 2);         // bf16 partials

    gates_kernel<<<MTOK / 4, 256, 0, stream>>>(x, b_seq, w_gates, g);
    scan_kernel<<<1, 1024, 0, stream>>>(b_seq, g, orig, g_c, cnt2);
    gather_cast_kernel<<<MTOK / 8, 256, 0, stream>>>(x, orig, cnt2, x_c, g_c);
    bias_init_kernel<<<(MTOK * DMODEL) / 256, 256, 0, stream>>>(g, b2, out);
    transpose_cast_kernel<<<dim3(DFF / 32, DMODEL / 32, NEXP), 256, 0, stream>>>(
        w1, w1t_all, DMODEL, DFF, DMODEL, (size_t)DMODEL * DFF, (size_t)DFF * DMODEL);
    transpose_cast_kernel<<<dim3(DMODEL / 32, DFF / 32, NEXP), 256, 0, stream>>>(
        w2, w2t_all, DFF, DMODEL, NEXP * DFF, (size_t)DFF * DMODEL, (size_t)DFF);

    for (int m0 = 0; m0 < MTOK; m0 += MC) {
      gemm8p<1><<<dim3(NEXP * DFF / 256, MC / 256, 1), 512, 0, stream>>>(
          x_c + (size_t)m0 * DMODEL, w1t_all, DMODEL, DMODEL, DMODEL,
          b1, g_c, h_all, m0, nullptr, 0, cnt2);
      gemm8p<2><<<dim3(DMODEL / 256, MC / 256, S), 512, 0, stream>>>(
          h_all, w2t_all, NEXP * DFF, NEXP * DFF, KS,
          nullptr, nullptr, nullptr, m0, part, (size_t)MC * DMODEL, cnt2);
      reduce_kernel<<<MC, 256, 0, stream>>>(
          part, out, orig, cnt2, m0, S, (size_t)MC * DMODEL);
    }
    return;
  }

  // ---------------- fallback: R1 path ----------------
  float* g = (float*)alloc((size_t)MTOK * 8 * 4);
  ushort* x_bf = (ushort*)alloc((size_t)MTOK * DMODEL * 2);
  ushort* w1t = (ushort*)alloc((size_t)DFF * DMODEL * 2);
  ushort* w2t = (ushort*)alloc((size_t)DMODEL * DFF * 2);
  size_t avail = (ws_size > off) ? (ws_size - off) : 0;
  long mc_l = (long)(avail / ((size_t)DFF * 2));
  int mc = (int)((mc_l / 128) * 128);
  if (mc > MTOK) mc = MTOK;
  if (mc < 128) mc = 128;
  ushort* h = (ushort*)alloc((size_t)mc * DFF * 2);

  gates_kernel<<<MTOK / 4, 256, 0, stream>>>(x, b_seq, w_gates, g);
  cast_x_kernel<<<2048, 256, 0, stream>>>(x, x_bf, MTOK * DMODEL / 4);
  bias_init_kernel<<<(MTOK * DMODEL) / 256, 256, 0, stream>>>(g, b2, out);

  for (int e = 0; e < NEXP; ++e) {
    transpose_cast_kernel<<<dim3(DFF / 32, DMODEL / 32, 1), 256, 0, stream>>>(
        w1 + (size_t)e * DMODEL * DFF, w1t, DMODEL, DFF, DMODEL, 0, 0);
    transpose_cast_kernel<<<dim3(DMODEL / 32, DFF / 32, 1), 256, 0, stream>>>(
        w2 + (size_t)e * DFF * DMODEL, w2t, DFF, DMODEL, DFF, 0, 0);
    for (int m0 = 0; m0 < MTOK; m0 += mc) {
      int rows = (MTOK - m0 < mc) ? (MTOK - m0) : mc;
      gemm1_kernel<<<dim3(DFF / 128, rows / 128), 256, 0, stream>>>(
          x_bf + (size_t)m0 * DMODEL, w1t, b1 + (size_t)e * DFF, g, h, m0, e);
      gemm2_kernel<<<dim3(DMODEL / 128, rows / 128), 256, 0, stream>>>(
          h, w2t, out + (size_t)m0 * DMODEL);
    }
  }
}

// Round 9
// 1140.270 us; speedup vs baseline: 1.0556x; 1.0556x over previous
//
#include <hip/hip_runtime.h>
#include <stdint.h>

// MMoE: M=8192 tokens, D=1024, F=4096, E=8 experts, T=4 tasks.
// out[tok] = sum_e gate[tok,e] * (relu(x@w1[e]+b1[e]) @ w2[e] + b2[e]); gate=0 row if b_seq==0.
// R9 = R6 (proven 1150us: serial phases, MC=1024, compaction, bf16 partials, R6 epilogue)
//      + gemm1 h-stores NON-TEMPORAL (h no longer evicts w1t from L3 -> weights L3-resident
//        across chunks; removes ~512MB HBM weight re-streaming)
//      + gemm2 XCD-grouped 1-D grid (4 N-blocks sharing an h-slice get same bid%8 -> same
//        XCD L2 -> h fetched from HBM once per slice, not 4x).
//      R8's C^T epilogue REVERTED (scattered 8B stores: 83.5->90.9us).

#define MTOK 8192
#define DMODEL 1024
#define DFF 4096
#define NEXP 8

typedef __attribute__((ext_vector_type(8))) short bf16x8;
typedef __attribute__((ext_vector_type(4))) float f32x4;
typedef __attribute__((ext_vector_type(4))) unsigned short u16x4;

typedef const __attribute__((address_space(1))) void* gas_ptr;
typedef __attribute__((address_space(3))) void* las_ptr;

__device__ __forceinline__ ushort f32_bf16(float f) {
  uint32_t u = __builtin_bit_cast(uint32_t, f);
  return (ushort)((u + 0x7FFFu + ((u >> 16) & 1u)) >> 16);
}

__device__ __forceinline__ float bf16_f32(ushort u) {
  return __builtin_bit_cast(float, (uint32_t)u << 16);
}

__device__ __forceinline__ void gload_lds16(const void* g, void* s) {
  __builtin_amdgcn_global_load_lds((gas_ptr)g, (las_ptr)s, 16, 0, 0);
}

__device__ __forceinline__ unsigned ldsOff(const void* p) {
  return (unsigned)(unsigned long long)(__attribute__((address_space(3))) const char*)p;
}

// ---------------- gates: one wave per token ----------------
__global__ __launch_bounds__(256) void gates_kernel(
    const float* __restrict__ x, const int* __restrict__ b_seq,
    const float* __restrict__ w_gates, float* __restrict__ g) {
  int wave = threadIdx.x >> 6;
  int lane = threadIdx.x & 63;
  int tok = blockIdx.x * 4 + wave;
  if (tok >= MTOK) return;
  int t = b_seq[tok];
  if (t == 0) {
    if (lane < 8) g[tok * 8 + lane] = 0.f;
    return;
  }
  const float* wg = w_gates + (size_t)(t - 1) * DMODEL * NEXP;
  const float* xr = x + (size_t)tok * DMODEL;
  float acc[8] = {0.f, 0.f, 0.f, 0.f, 0.f, 0.f, 0.f, 0.f};
  for (int d = lane; d < DMODEL; d += 64) {
    float xv = xr[d];
    const float* w = wg + (size_t)d * NEXP;
#pragma unroll
    for (int e = 0; e < 8; ++e) acc[e] = fmaf(xv, w[e], acc[e]);
  }
#pragma unroll
  for (int off = 32; off; off >>= 1) {
#pragma unroll
    for (int e = 0; e < 8; ++e) acc[e] += __shfl_xor(acc[e], off, 64);
  }
  if (lane == 0) {
    float m = acc[0];
#pragma unroll
    for (int e = 1; e < 8; ++e) m = fmaxf(m, acc[e]);
    float p[8]; float s = 0.f;
#pragma unroll
    for (int e = 0; e < 8; ++e) { p[e] = expf(acc[e] - m); s += p[e]; }
    float inv = 1.f / s;
#pragma unroll
    for (int e = 0; e < 8; ++e) g[tok * 8 + e] = p[e] * inv;
  }
}

// ---------------- compaction scan: deterministic, 1 block ----------------
__global__ __launch_bounds__(1024) void scan_kernel(
    const int* __restrict__ b_seq, const float* __restrict__ g,
    int* __restrict__ orig, float* __restrict__ g_c, int* __restrict__ cnt2) {
  __shared__ int s[1024];
  int t = threadIdx.x;
  int f[8]; int loc = 0;
  int base_tok = t * 8;
#pragma unroll
  for (int j = 0; j < 8; ++j) { f[j] = b_seq[base_tok + j] > 0; loc += f[j]; }
  s[t] = loc;
  __syncthreads();
  for (int off = 1; off < 1024; off <<= 1) {
    int v = (t >= off) ? s[t - off] : 0;
    __syncthreads();
    s[t] += v;
    __syncthreads();
  }
  int pos = s[t] - loc;
#pragma unroll
  for (int j = 0; j < 8; ++j) {
    if (f[j]) {
      orig[pos] = base_tok + j;
#pragma unroll
      for (int e = 0; e < 8; ++e) g_c[pos * 8 + e] = g[(base_tok + j) * 8 + e];
      pos++;
    }
  }
  if (t == 1023) {
    int count = s[1023];
    cnt2[0] = count;
    cnt2[1] = (count + 255) & ~255;
  }
}

// ---------------- cast x f32 -> bf16 (fallback path only) ----------------
__global__ __launch_bounds__(256) void cast_x_kernel(
    const float* __restrict__ x, ushort* __restrict__ xb, int n4) {
  int idx = blockIdx.x * blockDim.x + threadIdx.x;
  int stride = gridDim.x * blockDim.x;
  for (; idx < n4; idx += stride) {
    float4 v = ((const float4*)x)[idx];
    ushort4 o;
    o.x = f32_bf16(v.x); o.y = f32_bf16(v.y); o.z = f32_bf16(v.z); o.w = f32_bf16(v.w);
    ((ushort4*)xb)[idx] = o;
  }
}

// ------- gather + cast: x_c[r] = bf16(x[orig[r]]); zero pad rows (x and gates) -------
__global__ __launch_bounds__(256) void gather_cast_kernel(
    const float* __restrict__ x, const int* __restrict__ orig,
    const int* __restrict__ cnt2, ushort* __restrict__ x_c, float* __restrict__ g_c) {
  int r = blockIdx.x * 8 + (threadIdx.x >> 5);
  int cpad = cnt2[1];
  if (r >= cpad) return;
  int count = cnt2[0];
  int lane32 = threadIdx.x & 31;
  ushort4* dst = (ushort4*)(x_c + (size_t)r * DMODEL);
  if (r < count) {
    const float4* src = (const float4*)(x + (size_t)orig[r] * DMODEL);
    for (int j = lane32; j < 256; j += 32) {
      float4 v = src[j];
      ushort4 o;
      o.x = f32_bf16(v.x); o.y = f32_bf16(v.y); o.z = f32_bf16(v.z); o.w = f32_bf16(v.w);
      dst[j] = o;
    }
  } else {
    ushort4 z = {0, 0, 0, 0};
    for (int j = lane32; j < 256; j += 32) dst[j] = z;
    if (lane32 < 8) g_c[(size_t)r * 8 + lane32] = 0.f;
  }
}

// ---- transpose+cast: src f32 [R][C] -> dst bf16 [C][R] with dst ld + per-expert strides ----
__global__ __launch_bounds__(256) void transpose_cast_kernel(
    const float* __restrict__ src0, ushort* __restrict__ dst0, int R, int C,
    int ld_dst, size_t src_estride, size_t dst_estride) {
  const float* src = src0 + blockIdx.z * src_estride;
  ushort* dst = dst0 + blockIdx.z * dst_estride;
  __shared__ float tile[32][33];
  int tr = blockIdx.y, tc = blockIdx.x;
  int t = threadIdx.x;
  int r = t >> 3, c4 = (t & 7) * 4;
  float4 v = *(const float4*)&src[(size_t)(tr * 32 + r) * C + tc * 32 + c4];
  tile[r][c4 + 0] = v.x; tile[r][c4 + 1] = v.y; tile[r][c4 + 2] = v.z; tile[r][c4 + 3] = v.w;
  __syncthreads();
  ushort4 o;
  o.x = f32_bf16(tile[c4 + 0][r]);
  o.y = f32_bf16(tile[c4 + 1][r]);
  o.z = f32_bf16(tile[c4 + 2][r]);
  o.w = f32_bf16(tile[c4 + 3][r]);
  *(ushort4*)&dst[(size_t)(tc * 32 + r) * ld_dst + tr * 32 + c4] = o;
}

// ---------------- out init: out[n,d] = sum_e g[n,e]*b2[e,d] ----------------
__global__ __launch_bounds__(256) void bias_init_kernel(
    const float* __restrict__ g, const float* __restrict__ b2, float* __restrict__ out) {
  int idx = blockIdx.x * 256 + threadIdx.x;
  int tok = idx >> 10, d = idx & 1023;
  const float* gr = g + (size_t)tok * 8;
  float s = 0.f;
#pragma unroll
  for (int e = 0; e < 8; ++e) s = fmaf(gr[e], b2[(size_t)e * DMODEL + d], s);
  out[idx] = s;
}

// ================= 256x256 8-phase GEMM core (BK=64, 8 waves, 128KB LDS dbuf) =================
// EPI=1: H = gate * relu(A@Bt^T + b1)  (bf16, ld 32768), NON-TEMPORAL stores
// EPI=2: partial[z] = A@Bt^T over K-slice (bf16, ld 1024), normal stores
#define DS_READ(dst, addr) asm volatile("ds_read_b128 %0, %1" : "=v"(dst) : "v"(addr))

#define MFMA16(mh, BF) do { \
  acc[(mh)*4+0][0] = __builtin_amdgcn_mfma_f32_16x16x32_bf16(aF[0], BF[0], acc[(mh)*4+0][0],0,0,0); \
  acc[(mh)*4+0][1] = __builtin_amdgcn_mfma_f32_16x16x32_bf16(aF[0], BF[1], acc[(mh)*4+0][1],0,0,0); \
  acc[(mh)*4+0][2] = __builtin_amdgcn_mfma_f32_16x16x32_bf16(aF[0], BF[2], acc[(mh)*4+0][2],0,0,0); \
  acc[(mh)*4+0][3] = __builtin_amdgcn_mfma_f32_16x16x32_bf16(aF[0], BF[3], acc[(mh)*4+0][3],0,0,0); \
  acc[(mh)*4+1][0] = __builtin_amdgcn_mfma_f32_16x16x32_bf16(aF[1], BF[0], acc[(mh)*4+1][0],0,0,0); \
  acc[(mh)*4+1][1] = __builtin_amdgcn_mfma_f32_16x16x32_bf16(aF[1], BF[1], acc[(mh)*4+1][1],0,0,0); \
  acc[(mh)*4+1][2] = __builtin_amdgcn_mfma_f32_16x16x32_bf16(aF[1], BF[2], acc[(mh)*4+1][2],0,0,0); \
  acc[(mh)*4+1][3] = __builtin_amdgcn_mfma_f32_16x16x32_bf16(aF[1], BF[3], acc[(mh)*4+1][3],0,0,0); \
  acc[(mh)*4+2][0] = __builtin_amdgcn_mfma_f32_16x16x32_bf16(aF[2], BF[0], acc[(mh)*4+2][0],0,0,0); \
  acc[(mh)*4+2][1] = __builtin_amdgcn_mfma_f32_16x16x32_bf16(aF[2], BF[1], acc[(mh)*4+2][1],0,0,0); \
  acc[(mh)*4+2][2] = __builtin_amdgcn_mfma_f32_16x16x32_bf16(aF[2], BF[2], acc[(mh)*4+2][2],0,0,0); \
  acc[(mh)*4+2][3] = __builtin_amdgcn_mfma_f32_16x16x32_bf16(aF[2], BF[3], acc[(mh)*4+2][3],0,0,0); \
  acc[(mh)*4+3][0] = __builtin_amdgcn_mfma_f32_16x16x32_bf16(aF[3], BF[0], acc[(mh)*4+3][0],0,0,0); \
  acc[(mh)*4+3][1] = __builtin_amdgcn_mfma_f32_16x16x32_bf16(aF[3], BF[1], acc[(mh)*4+3][1],0,0,0); \
  acc[(mh)*4+3][2] = __builtin_amdgcn_mfma_f32_16x16x32_bf16(aF[3], BF[2], acc[(mh)*4+3][2],0,0,0); \
  acc[(mh)*4+3][3] = __builtin_amdgcn_mfma_f32_16x16x32_bf16(aF[3], BF[3], acc[(mh)*4+3][3],0,0,0); \
} while (0)

#define PH_READS_A(mh, kx) do { \
  DS_READ(aF[0], ab + (mh)*8192 +    0 + (kx)); \
  DS_READ(aF[1], ab + (mh)*8192 + 2048 + (kx)); \
  DS_READ(aF[2], ab + (mh)*8192 + 4096 + (kx)); \
  DS_READ(aF[3], ab + (mh)*8192 + 6144 + (kx)); \
} while (0)

#define PH_READS_B(BF, kx) do { \
  DS_READ(BF[0], bb +    0 + (kx)); \
  DS_READ(BF[1], bb + 2048 + (kx)); \
  DS_READ(BF[2], bb + 4096 + (kx)); \
  DS_READ(BF[3], bb + 6144 + (kx)); \
} while (0)

#define PH_TAIL(mh, BF, CLOSE) do { \
  __builtin_amdgcn_s_barrier(); \
  asm volatile("s_waitcnt lgkmcnt(0)" ::: "memory"); \
  __builtin_amdgcn_sched_barrier(0); \
  __builtin_amdgcn_s_setprio(1); \
  MFMA16(mh, BF); \
  __builtin_amdgcn_s_setprio(0); \
  if (CLOSE) __builtin_amdgcn_s_barrier(); \
} while (0)

template <int EPI>
__device__ __forceinline__ void gemm_core(
    char* ldsc,
    const ushort* __restrict__ A, const ushort* __restrict__ Bt,
    int ldA, int ldB, int K_len,
    const float* __restrict__ Bias, const float* __restrict__ Gates,
    ushort* __restrict__ H, int m_off,
    ushort* __restrict__ PoutBf, size_t PsliceElems,
    const int* __restrict__ cnt2, int bx, int by, int bz) {
  if (m_off + by * 256 >= cnt2[1]) return;  // compaction guard (block-uniform)

  const int tid = threadIdx.x;
  const int lane = tid & 63;
  const int wid = tid >> 6;
  const int wm = wid >> 2;   // 0..1
  const int wn = wid & 3;    // 0..3
  const int tileM = by * 256;
  const int tileN = bx * 256;
  const int kbeg = bz * K_len;

  const ushort* Arow0 = A + (size_t)tileM * ldA + kbeg;
  const ushort* Brow0 = Bt + (size_t)tileN * ldB + kbeg;
  const unsigned lds0 = ldsOff(ldsc);
  const unsigned abase = lds0 + (wm * 128 + (lane & 15)) * 128;
  const unsigned bbase = lds0 + 32768 + (wn * 64 + (lane & 15)) * 128;
  const unsigned kx0 = (unsigned)(((lane >> 4) << 4) ^ ((lane & 7) << 4));
  const unsigned kx1 = kx0 ^ 64u;

  f32x4 acc[8][4];
#pragma unroll
  for (int i = 0; i < 8; ++i)
#pragma unroll
    for (int j = 0; j < 4; ++j) acc[i][j] = (f32x4){0.f, 0.f, 0.f, 0.f};

  const int rr = tid >> 3;
  const int scol = ((tid & 7) << 4) ^ ((rr & 7) << 4);
  auto STAGE = [&](int buf, int isB, int hh, int kt2) {
    const ushort* gsrc = isB ? Brow0 : Arow0;
    const int ld = isB ? ldB : ldA;
    char* region = ldsc + buf * 65536 + isB * 32768 + hh * 16384;
#pragma unroll
    for (int j = 0; j < 2; ++j) {
      int row = j * 64 + rr;
      const char* src = (const char*)(gsrc + (size_t)(hh * 128 + row) * ld + kt2 * 64) + scol;
      gload_lds16(src, region + (j * 512 + tid) * 16);
    }
  };

  bf16x8 aF[4], bF0[4], bF1[4];
  const int NT = K_len >> 6;

  STAGE(0, 1, 0, 0); STAGE(0, 1, 1, 0); STAGE(0, 0, 0, 0); STAGE(0, 0, 1, 0);
  if (NT > 1) STAGE(1, 1, 0, 1);
  asm volatile("s_waitcnt vmcnt(2)" ::: "memory");
  __builtin_amdgcn_s_barrier();

  for (int kt = 0; kt < NT; ++kt) {
    const int cur = kt & 1;
    const int oth = cur ^ 1;
    const unsigned bufoff = (unsigned)cur << 16;
    const unsigned ab = abase + bufoff;
    const unsigned bb = bbase + bufoff;
    const bool s1 = (kt + 1 < NT), s2 = (kt + 2 < NT);
    PH_READS_A(0, kx0); PH_READS_B(bF0, kx0);
    if (s1) STAGE(oth, 1, 1, kt + 1);
    PH_TAIL(0, bF0, true);
    PH_READS_A(1, kx0);
    if (s1) STAGE(oth, 0, 0, kt + 1);
    PH_TAIL(1, bF0, true);
    PH_READS_A(0, kx1); PH_READS_B(bF1, kx1);
    if (s1) STAGE(oth, 0, 1, kt + 1);
    PH_TAIL(0, bF1, true);
    PH_READS_A(1, kx1);
    if (s2) STAGE(cur, 1, 0, kt + 2);
    PH_TAIL(1, bF1, false);
    if (s1) {
      if (s2) asm volatile("s_waitcnt vmcnt(2)" ::: "memory");
      else    asm volatile("s_waitcnt vmcnt(0)" ::: "memory");
      __builtin_amdgcn_s_barrier();
    }
  }

  // ---- R6 epilogue layout (col = lane&15: 16-lane-contiguous stores) ----
  const int colBase = tileN + wn * 64 + (lane & 15);
  const int rowBase = tileM + wm * 128 + ((lane >> 4) << 2);
  if constexpr (EPI == 1) {
    const int e = tileN >> 12;  // 256-wide tile never crosses expert boundary
    float bias[4];
#pragma unroll
    for (int nf = 0; nf < 4; ++nf) bias[nf] = Bias[colBase + nf * 16];
#pragma unroll
    for (int mf = 0; mf < 8; ++mf) {
#pragma unroll
      for (int q = 0; q < 4; ++q) {
        const int row = rowBase + mf * 16 + q;
        const float gv = Gates[(size_t)(m_off + row) * 8 + e];
#pragma unroll
        for (int nf = 0; nf < 4; ++nf) {
          float v = fmaxf(acc[mf][nf][q] + bias[nf], 0.f) * gv;
          __builtin_nontemporal_store(f32_bf16(v),
              &H[(size_t)row * 32768 + colBase + nf * 16]);
        }
      }
    }
  } else {
    ushort* Pb = PoutBf + (size_t)bz * PsliceElems;
#pragma unroll
    for (int mf = 0; mf < 8; ++mf) {
#pragma unroll
      for (int q = 0; q < 4; ++q) {
        const int row = rowBase + mf * 16 + q;
#pragma unroll
        for (int nf = 0; nf < 4; ++nf)
          Pb[(size_t)row * 1024 + colBase + nf * 16] = f32_bf16(acc[mf][nf][q]);
      }
    }
  }
}

// ---- gemm1: grid (128 N-tiles, 4 M-tiles) ----
__global__ __launch_bounds__(512, 2) void gemm1_8p(
    const ushort* __restrict__ A, const ushort* __restrict__ Bt,
    const float* __restrict__ Bias, const float* __restrict__ Gates,
    ushort* __restrict__ H, int m_off, const int* __restrict__ cnt2) {
  __shared__ __align__(16) char lds[131072];
  gemm_core<1>(lds, A, Bt, DMODEL, DMODEL, DMODEL,
               Bias, Gates, H, m_off, nullptr, 0, cnt2,
               blockIdx.x, blockIdx.y, 0);
}

// ---- gemm2: 1-D grid 256, XCD-grouped decode so the 4 N-blocks sharing one h-slice
//      (same M-tile, same K-slice) land on the same XCD (same bid%8 -> same L2) ----
__global__ __launch_bounds__(512, 2) void gemm2_8p(
    const ushort* __restrict__ A, const ushort* __restrict__ Bt,
    ushort* __restrict__ Pout, size_t Pslice, int m_off,
    const int* __restrict__ cnt2) {
  __shared__ __align__(16) char lds[131072];
  const int bid = blockIdx.x;        // 0..255
  const int c = bid & 7;             // XCD (dispatch round-robins bid%8)
  const int s = bid >> 3;            // 0..31
  const int p = c + 8 * (s >> 2);    // 0..63 = (M-tile, K-slice) pair
  const int n = s & 3;               // N-tile 0..3
  const int y = p & 3;               // M-tile 0..3
  const int z = p >> 2;              // K-slice 0..15
  gemm_core<2>(lds, A, Bt, NEXP * DFF, NEXP * DFF, 2048,
               nullptr, nullptr, nullptr, m_off, Pout, Pslice, cnt2, n, y, z);
}

// ------- reduce: out[orig[gr]] += sum_s part[s][r]  (bf16 partials, scatter, count guard) -------
__global__ __launch_bounds__(256) void reduce_kernel(
    const ushort* __restrict__ Pb, float* __restrict__ out,
    const int* __restrict__ orig, const int* __restrict__ cnt2,
    int m_off, int S, size_t sstride) {
  int i = blockIdx.x * 256 + threadIdx.x;
  int r = i >> 8;
  int d4 = i & 255;
  int gr = m_off + r;
  if (gr >= cnt2[0]) return;
  float4* orow = (float4*)(out + (size_t)orig[gr] * 1024);
  float4 a = orow[d4];
  for (int s = 0; s < S; ++s) {
    u16x4 v = *((const u16x4*)(Pb + (size_t)s * sstride + (size_t)r * 1024) + d4);
    a.x += bf16_f32(v.x); a.y += bf16_f32(v.y); a.z += bf16_f32(v.z); a.w += bf16_f32(v.w);
  }
  orow[d4] = a;
}

// ================= R1 fallback kernels (128x128, m97-structure) =================
__global__ __launch_bounds__(256) void gemm1_kernel(
    const ushort* __restrict__ A, const ushort* __restrict__ Bt,
    const float* __restrict__ b1e, const float* __restrict__ g,
    ushort* __restrict__ H, int m_off, int e) {
  __shared__ ushort As[128 * 32];
  __shared__ ushort Bs[128 * 32];
  const int tid = threadIdx.x;
  const int lane = tid & 63;
  const int wid = tid >> 6;
  const int wm = wid >> 1, wn = wid & 1;
  const int tileM = blockIdx.y * 128;
  const int tileN = blockIdx.x * 128;
  f32x4 zero = {0.f, 0.f, 0.f, 0.f};
  f32x4 acc[4][4];
#pragma unroll
  for (int i = 0; i < 4; ++i)
#pragma unroll
    for (int j = 0; j < 4; ++j) acc[i][j] = zero;
  const int r0 = tid >> 2;
  const int cb = (tid & 3) << 4;
  const char* gA = (const char*)(A + (size_t)(tileM + r0) * DMODEL) + cb;
  const char* gB = (const char*)(Bt + (size_t)(tileN + r0) * DMODEL) + cb;
  char* lA = (char*)As + r0 * 64 + cb;
  char* lB = (char*)Bs + r0 * 64 + cb;
  const int lrow = lane & 15;
  const int lk = (lane >> 4) << 3;
  for (int k0 = 0; k0 < DMODEL; k0 += 32) {
    const size_t kb = (size_t)k0 * 2;
    gload_lds16(gA + kb, lA);
    gload_lds16(gA + kb + (size_t)64 * DMODEL * 2, lA + 4096);
    gload_lds16(gB + kb, lB);
    gload_lds16(gB + kb + (size_t)64 * DMODEL * 2, lB + 4096);
    __syncthreads();
    bf16x8 af[4], bfv[4];
#pragma unroll
    for (int i = 0; i < 4; ++i) {
      af[i] = *(const bf16x8*)&As[(wm * 64 + i * 16 + lrow) * 32 + lk];
      bfv[i] = *(const bf16x8*)&Bs[(wn * 64 + i * 16 + lrow) * 32 + lk];
    }
#pragma unroll
    for (int i = 0; i < 4; ++i)
#pragma unroll
      for (int j = 0; j < 4; ++j)
        acc[i][j] = __builtin_amdgcn_mfma_f32_16x16x32_bf16(af[i], bfv[j], acc[i][j], 0, 0, 0);
    __syncthreads();
  }
#pragma unroll
  for (int i = 0; i < 4; ++i) {
#pragma unroll
    for (int j = 0; j < 4; ++j) {
      int col = tileN + wn * 64 + j * 16 + (lane & 15);
      float bias = b1e[col];
#pragma unroll
      for (int q = 0; q < 4; ++q) {
        int row = tileM + wm * 64 + i * 16 + ((lane >> 4) << 2) + q;
        float gv = g[(size_t)(m_off + row) * 8 + e];
        float v = fmaxf(acc[i][j][q] + bias, 0.f) * gv;
        H[(size_t)row * DFF + col] = f32_bf16(v);
      }
    }
  }
}

__global__ __launch_bounds__(256) void gemm2_kernel(
    const ushort* __restrict__ A, const ushort* __restrict__ Bt,
    float* __restrict__ out) {
  __shared__ ushort As[128 * 32];
  __shared__ ushort Bs[128 * 32];
  const int tid = threadIdx.x;
  const int lane = tid & 63;
  const int wid = tid >> 6;
  const int wm = wid >> 1, wn = wid & 1;
  const int tileM = blockIdx.y * 128;
  const int tileN = blockIdx.x * 128;
  f32x4 zero = {0.f, 0.f, 0.f, 0.f};
  f32x4 acc[4][4];
#pragma unroll
  for (int i = 0; i < 4; ++i)
#pragma unroll
    for (int j = 0; j < 4; ++j) acc[i][j] = zero;
  const int r0 = tid >> 2;
  const int cb = (tid & 3) << 4;
  const char* gA = (const char*)(A + (size_t)(tileM + r0) * DFF) + cb;
  const char* gB = (const char*)(Bt + (size_t)(tileN + r0) * DFF) + cb;
  char* lA = (char*)As + r0 * 64 + cb;
  char* lB = (char*)Bs + r0 * 64 + cb;
  const int lrow = lane & 15;
  const int lk = (lane >> 4) << 3;
  for (int k0 = 0; k0 < DFF; k0 += 32) {
    const size_t kb = (size_t)k0 * 2;
    gload_lds16(gA + kb, lA);
    gload_lds16(gA + kb + (size_t)64 * DFF * 2, lA + 4096);
    gload_lds16(gB + kb, lB);
    gload_lds16(gB + kb + (size_t)64 * DFF * 2, lB + 4096);
    __syncthreads();
    bf16x8 af[4], bfv[4];
#pragma unroll
    for (int i = 0; i < 4; ++i) {
      af[i] = *(const bf16x8*)&As[(wm * 64 + i * 16 + lrow) * 32 + lk];
      bfv[i] = *(const bf16x8*)&Bs[(wn * 64 + i * 16 + lrow) * 32 + lk];
    }
#pragma unroll
    for (int i = 0; i < 4; ++i)
#pragma unroll
      for (int j = 0; j < 4; ++j)
        acc[i][j] = __builtin_amdgcn_mfma_f32_16x16x32_bf16(af[i], bfv[j], acc[i][j], 0, 0, 0);
    __syncthreads();
  }
#pragma unroll
  for (int i = 0; i < 4; ++i) {
#pragma unroll
    for (int j = 0; j < 4; ++j) {
      int col = tileN + wn * 64 + j * 16 + (lane & 15);
#pragma unroll
      for (int q = 0; q < 4; ++q) {
        int row = tileM + wm * 64 + i * 16 + ((lane >> 4) << 2) + q;
        size_t o = (size_t)row * DMODEL + col;
        out[o] += acc[i][j][q];
      }
    }
  }
}

extern "C" void kernel_launch(void* const* d_in, const int* in_sizes, int n_in,
                              void* d_out, int out_size, void* d_ws, size_t ws_size,
                              hipStream_t stream) {
  const float* x = (const float*)d_in[0];
  const int* b_seq = (const int*)d_in[1];
  const float* w1 = (const float*)d_in[2];
  const float* b1 = (const float*)d_in[3];
  const float* w2 = (const float*)d_in[4];
  const float* b2 = (const float*)d_in[5];
  const float* w_gates = (const float*)d_in[6];
  float* out = (float*)d_out;

  char* ws = (char*)d_ws;
  size_t off = 0;
  auto alloc = [&](size_t bytes) {
    char* p = ws + off;
    off += (bytes + 255) & ~(size_t)255;
    return p;
  };

  const int MC = 1024, S = 16;
  const size_t need_fused =
      (size_t)MTOK * 8 * 4 + 512 +            // g
      (size_t)MTOK * 4 + 512 +                // orig
      1024 +                                  // cnt2
      (size_t)MTOK * 8 * 4 + 512 +            // g_c
      (size_t)MTOK * DMODEL * 2 + 512 +       // x_c
      (size_t)NEXP * DFF * DMODEL * 2 + 512 + // w1t_all
      (size_t)NEXP * DFF * DMODEL * 2 + 512 + // w2t_all
      (size_t)MC * NEXP * DFF * 2 + 512 +     // h chunk (64 MB)
      (size_t)S * MC * DMODEL * 2 + 512;      // bf16 partials (32 MB)

  if (ws_size >= need_fused) {
    float* g = (float*)alloc((size_t)MTOK * 8 * 4);
    int* orig = (int*)alloc((size_t)MTOK * 4);
    int* cnt2 = (int*)alloc(64);
    float* g_c = (float*)alloc((size_t)MTOK * 8 * 4);
    ushort* x_c = (ushort*)alloc((size_t)MTOK * DMODEL * 2);
    ushort* w1t_all = (ushort*)alloc((size_t)NEXP * DFF * DMODEL * 2);  // [E*F][D]
    ushort* w2t_all = (ushort*)alloc((size_t)DMODEL * NEXP * DFF * 2);  // [D][E*F]
    ushort* h_all = (ushort*)alloc((size_t)MC * NEXP * DFF * 2);        // [MC][E*F]
    ushort* part = (ushort*)alloc((size_t)S * MC * DMODEL * 2);         // bf16 partials

    gates_kernel<<<MTOK / 4, 256, 0, stream>>>(x, b_seq, w_gates, g);
    scan_kernel<<<1, 1024, 0, stream>>>(b_seq, g, orig, g_c, cnt2);
    gather_cast_kernel<<<MTOK / 8, 256, 0, stream>>>(x, orig, cnt2, x_c, g_c);
    bias_init_kernel<<<(MTOK * DMODEL) / 256, 256, 0, stream>>>(g, b2, out);
    transpose_cast_kernel<<<dim3(DFF / 32, DMODEL / 32, NEXP), 256, 0, stream>>>(
        w1, w1t_all, DMODEL, DFF, DMODEL, (size_t)DMODEL * DFF, (size_t)DFF * DMODEL);
    transpose_cast_kernel<<<dim3(DMODEL / 32, DFF / 32, NEXP), 256, 0, stream>>>(
        w2, w2t_all, DFF, DMODEL, NEXP * DFF, (size_t)DFF * DMODEL, (size_t)DFF);

    for (int m0 = 0; m0 < MTOK; m0 += MC) {
      gemm1_8p<<<dim3(NEXP * DFF / 256, MC / 256), 512, 0, stream>>>(
          x_c + (size_t)m0 * DMODEL, w1t_all, b1, g_c, h_all, m0, cnt2);
      gemm2_8p<<<256, 512, 0, stream>>>(
          h_all, w2t_all, part, (size_t)MC * DMODEL, m0, cnt2);
      reduce_kernel<<<MC, 256, 0, stream>>>(
          part, out, orig, cnt2, m0, S, (size_t)MC * DMODEL);
    }
    return;
  }

  // ---------------- fallback: R1 path ----------------
  float* g = (float*)alloc((size_t)MTOK * 8 * 4);
  ushort* x_bf = (ushort*)alloc((size_t)MTOK * DMODEL * 2);
  ushort* w1t = (ushort*)alloc((size_t)DFF * DMODEL * 2);
  ushort* w2t = (ushort*)alloc((size_t)DMODEL * DFF * 2);
  size_t avail = (ws_size > off) ? (ws_size - off) : 0;
  long mc_l = (long)(avail / ((size_t)DFF * 2));
  int mc = (int)((mc_l / 128) * 128);
  if (mc > MTOK) mc = MTOK;
  if (mc < 128) mc = 128;
  ushort* h = (ushort*)alloc((size_t)mc * DFF * 2);

  gates_kernel<<<MTOK / 4, 256, 0, stream>>>(x, b_seq, w_gates, g);
  cast_x_kernel<<<2048, 256, 0, stream>>>(x, x_bf, MTOK * DMODEL / 4);
  bias_init_kernel<<<(MTOK * DMODEL) / 256, 256, 0, stream>>>(g, b2, out);

  for (int e = 0; e < NEXP; ++e) {
    transpose_cast_kernel<<<dim3(DFF / 32, DMODEL / 32, 1), 256, 0, stream>>>(
        w1 + (size_t)e * DMODEL * DFF, w1t, DMODEL, DFF, DMODEL, 0, 0);
    transpose_cast_kernel<<<dim3(DMODEL / 32, DFF / 32, 1), 256, 0, stream>>>(
        w2 + (size_t)e * DFF * DMODEL, w2t, DFF, DMODEL, DFF, 0, 0);
    for (int m0 = 0; m0 < MTOK; m0 += mc) {
      int rows = (MTOK - m0 < mc) ? (MTOK - m0) : mc;
      gemm1_kernel<<<dim3(DFF / 128, rows / 128), 256, 0, stream>>>(
          x_bf + (size_t)m0 * DMODEL, w1t, b1 + (size_t)e * DFF, g, h, m0, e);
      gemm2_kernel<<<dim3(DMODEL / 128, rows / 128), 256, 0, stream>>>(
          h, w2t, out + (size_t)m0 * DMODEL);
    }
  }
}